// Round 1
// baseline (598.552 us; speedup 1.0000x reference)
//
#include <hip/hip_runtime.h>
#include <hip/hip_bf16.h>
#include <stdint.h>

// SLAYER SNN pipeline, MI355X.
// Layouts: raw input NCHWT (t innermost). All intermediate activations NCTHW
// (spatial innermost) so both conv tile loads and time-scan loads are coalesced.
// Precision: conv/cumsum/scan path in f64 (spike flips are the failure mode).
// Spikes stored as u8 (exact); spike pooling = int sum / 16 (exact in f32).

#define T_ 100

// ---------------- K1: avgpool4 on raw input, NCHWT -> NCTHW f64 --------------
// grid: 8*2*64 blocks (n,c,h'), block 256.
// in: data [8][2][256][256][100] f32 ; out: pooled0 [8][2][100][64][64] f64
__global__ __launch_bounds__(256) void k1_pool0(const float* __restrict__ in,
                                                double* __restrict__ out) {
    __shared__ double lds[64 * 101];
    int b = blockIdx.x;
    int h = b & 63, c = (b >> 6) & 1, n = b >> 7;
    const float* inb = in + ((size_t)((n * 2 + c) * 256 + 4 * h) * 256) * 100;
    // phase A: pooled values; oi = w*100 + t  (lanes consecutive in t -> coalesced reads)
    for (int k = 0; k < 25; ++k) {
        int oi = threadIdx.x + (k << 8);       // 0..6399
        int w = oi / 100, t = oi % 100;
        double s = 0.0;
        #pragma unroll
        for (int a = 0; a < 4; ++a) {
            #pragma unroll
            for (int bb = 0; bb < 4; ++bb)
                s += (double)inb[((size_t)(a * 256 + 4 * w + bb)) * 100 + t];
        }
        lds[w * 101 + t] = s * 0.0625;
    }
    __syncthreads();
    // phase B: write NCTHW (lanes consecutive in w -> coalesced 512B stores)
    double* outb = out + ((size_t)(n * 2 + c) * 100) * 4096 + h * 64;
    for (int k = 0; k < 25; ++k) {
        int oi = threadIdx.x + (k << 8);
        int t = oi >> 6, w = oi & 63;
        outb[(size_t)t * 4096 + w] = lds[w * 101 + t];
    }
}

// ------- K2: conv7x7 (2->4ch) + cumsum + IAF scan, fused over t-chunks -------
// grid: 8*64 (n,h), block 128: tid = cog*64 + w; thread owns co {2cog,2cog+1}.
// pooled0 [8][2][100][64][64] f64 -> s0 [8][4][100][64][64] u8
#define TC2 5
__global__ __launch_bounds__(128) void k2_conv0_scan(const double* __restrict__ pooled0,
                                                     const float* __restrict__ wc0,
                                                     uint8_t* __restrict__ s0) {
    __shared__ double tile[2 * 7 * TC2 * 70];   // [ci][r][tt][ww] 39.2 KB
    int b = blockIdx.x;
    int h = b & 63, n = b >> 6;
    int tid = threadIdx.x;
    int w = tid & 63, cog = tid >> 6;
    int co0 = 2 * cog, co1 = co0 + 1;

    for (int i = tid; i < 2 * 7 * TC2 * 70; i += 128) tile[i] = 0.0;

    double p0 = 0.0, p1 = 0.0;
    int c0 = 0, c1 = 0;

    for (int ch = 0; ch < T_ / TC2; ++ch) {
        int t0 = ch * TC2;
        __syncthreads();
        // load 2ci x 5tt x 7r rows of 64 w (coalesced 512B global reads,
        // lane-consecutive LDS writes). OOB rows stay zero.
        for (int k = 0; k < 35; ++k) {
            int e = tid + (k << 7);            // 0..4479
            int ww = e & 63, rowid = e >> 6;   // 0..69
            int ci = rowid / 35, rem = rowid % 35;
            int tt = rem / 7, r = rem % 7;
            int habs = h - 3 + r;
            if ((unsigned)habs < 64u)
                tile[((ci * 7 + r) * TC2 + tt) * 70 + ww + 3] =
                    pooled0[((size_t)((n * 2 + ci) * 100 + t0 + tt)) * 4096 + habs * 64 + ww];
        }
        __syncthreads();

        double acc0[TC2], acc1[TC2];
        #pragma unroll
        for (int tt = 0; tt < TC2; ++tt) { acc0[tt] = 0.0; acc1[tt] = 0.0; }

        for (int ci = 0; ci < 2; ++ci) {
            for (int kh = 0; kh < 7; ++kh) {
                const double* trow = &tile[((ci * 7 + kh) * TC2) * 70];
                const float* wr0 = &wc0[co0 * 98 + ci * 49 + kh * 7];
                const float* wr1 = &wc0[co1 * 98 + ci * 49 + kh * 7];
                #pragma unroll
                for (int kw = 0; kw < 7; ++kw) {
                    double wa = (double)wr0[kw];
                    double wb = (double)wr1[kw];
                    #pragma unroll
                    for (int tt = 0; tt < TC2; ++tt) {
                        double v = trow[tt * 70 + w + kw];  // lane-consecutive: conflict-free
                        acc0[tt] += v * wa;
                        acc1[tt] += v * wb;
                    }
                }
            }
        }
        // cumsum + spike scan (reset-by-subtraction, theta=1)
        #pragma unroll
        for (int tt = 0; tt < TC2; ++tt) {
            size_t ob = ((size_t)((n * 4 + co0) * 100 + t0 + tt)) * 4096 + h * 64 + w;
            p0 += acc0[tt];
            int sp0 = (p0 - (double)c0) >= 1.0;
            c0 += sp0;
            s0[ob] = (uint8_t)sp0;
            size_t ob1 = ((size_t)((n * 4 + co1) * 100 + t0 + tt)) * 4096 + h * 64 + w;
            p1 += acc1[tt];
            int sp1 = (p1 - (double)c1) >= 1.0;
            c1 += sp1;
            s0[ob1] = (uint8_t)sp1;
        }
    }
}

// ---------------- K3: avgpool4 of spikes (exact) -----------------------------
// s0 [8][4][100][64][64] u8 -> pooled1 [8][4][100][16][16] f32
__global__ __launch_bounds__(256) void k3_pool1(const uint8_t* __restrict__ s0,
                                                float* __restrict__ pooled1) {
    int oi = blockIdx.x * 256 + threadIdx.x;   // 819200 outputs
    int w = oi & 15, h = (oi >> 4) & 15;
    int tc = oi >> 8;
    int t = tc % 100, nc = tc / 100;
    const uint8_t* base = s0 + ((size_t)nc * 100 + t) * 4096;
    int isum = 0;
    #pragma unroll
    for (int a = 0; a < 4; ++a) {
        #pragma unroll
        for (int bb = 0; bb < 4; ++bb)
            isum += base[(4 * h + a) * 64 + 4 * w + bb];
    }
    pooled1[oi] = (float)isum * 0.0625f;
}

// ---------------- K4a: conv7x7 (4->8ch) in f64 -------------------------------
// grid 800 (n,t), block 256 (h,w). pooled1 -> x1 [8][8][100][16][16] f64
__global__ __launch_bounds__(256) void k4a_conv1(const float* __restrict__ pooled1,
                                                 const float* __restrict__ wc1,
                                                 double* __restrict__ x1) {
    __shared__ float tile[4 * 22 * 24];   // [ci][hr][ww] 8.4 KB, zero-padded
    int b = blockIdx.x;
    int n = b / 100, t = b % 100;
    int tid = threadIdx.x;
    for (int i = tid; i < 4 * 22 * 24; i += 256) tile[i] = 0.0f;
    __syncthreads();
    for (int k = 0; k < 4; ++k) {
        int e = tid + (k << 8);            // 0..1023
        int w = e & 15, rowid = e >> 4;    // 0..63
        int ci = rowid >> 4, hr3 = rowid & 15;
        tile[(ci * 22 + hr3 + 3) * 24 + 3 + w] =
            pooled1[((size_t)((n * 4 + ci) * 100 + t)) * 256 + hr3 * 16 + w];
    }
    __syncthreads();
    int h = tid >> 4, w = tid & 15;
    double acc[8];
    #pragma unroll
    for (int co = 0; co < 8; ++co) acc[co] = 0.0;
    for (int ci = 0; ci < 4; ++ci) {
        for (int kh = 0; kh < 7; ++kh) {
            const float* trow = &tile[(ci * 22 + h + kh) * 24];
            const float* wr = &wc1[ci * 49 + kh * 7];
            #pragma unroll
            for (int kw = 0; kw < 7; ++kw) {
                double v = (double)trow[w + kw];
                #pragma unroll
                for (int co = 0; co < 8; ++co)
                    acc[co] += v * (double)wr[co * 196 + kw];
            }
        }
    }
    #pragma unroll
    for (int co = 0; co < 8; ++co)
        x1[((size_t)((n * 8 + co) * 100 + t)) * 256 + tid] = acc[co];
}

// ---------------- K4b: cumsum + IAF scan for stage 2 -------------------------
// grid 64 (n*8+co), block 256 (h*w plane). x1 f64 -> s1 u8, coalesced per t.
__global__ __launch_bounds__(256) void k4b_scan1(const double* __restrict__ x1,
                                                 uint8_t* __restrict__ s1) {
    size_t base = (size_t)blockIdx.x * 100 * 256 + threadIdx.x;
    double p = 0.0;
    int cnt = 0;
    for (int t = 0; t < T_; ++t) {
        p += x1[base + (size_t)t * 256];
        int sp = (p - (double)cnt) >= 1.0;
        cnt += sp;
        s1[base + (size_t)t * 256] = (uint8_t)sp;
    }
}

// ---------------- K5: avgpool4 + dense, fused block reduction ----------------
// grid 800 (n,t), block 256. s1 [8][8][100][16][16] u8 -> out [8][2][100] f32
__global__ __launch_bounds__(256) void k5_dense(const uint8_t* __restrict__ s1,
                                                const float* __restrict__ wd,
                                                float* __restrict__ out) {
    __shared__ float red[2][4];
    int b = blockIdx.x;
    int n = b / 100, t = b % 100;
    int tid = threadIdx.x;
    int c = tid >> 5, H = (tid >> 1) & 15, Wg = tid & 1;
    const uint8_t* sb = s1 + ((size_t)((n * 8 + c) * 100 + t)) * 256 + H * 16 + Wg * 8;
    float sumA = 0.f, sumB = 0.f;
    #pragma unroll
    for (int j = 0; j < 4; ++j) sumA += (float)sb[j];
    #pragma unroll
    for (int j = 4; j < 8; ++j) sumB += (float)sb[j];
    int wb = c * 16 + (H >> 2) * 4 + Wg * 2;
    float o0 = sumA * wd[wb] + sumB * wd[wb + 1];
    float o1 = sumA * wd[128 + wb] + sumB * wd[128 + wb + 1];
    #pragma unroll
    for (int off = 32; off > 0; off >>= 1) {
        o0 += __shfl_down(o0, off, 64);
        o1 += __shfl_down(o1, off, 64);
    }
    int lane = tid & 63, wid = tid >> 6;
    if (lane == 0) { red[0][wid] = o0; red[1][wid] = o1; }
    __syncthreads();
    if (tid == 0) {
        float a = (red[0][0] + red[0][1]) + (red[0][2] + red[0][3]);
        float bsum = (red[1][0] + red[1][1]) + (red[1][2] + red[1][3]);
        out[(size_t)(n * 2) * 100 + t] = a * 0.0625f;
        out[(size_t)(n * 2 + 1) * 100 + t] = bsum * 0.0625f;
    }
}

extern "C" void kernel_launch(void* const* d_in, const int* in_sizes, int n_in,
                              void* d_out, int out_size, void* d_ws, size_t ws_size,
                              hipStream_t stream) {
    const float* data = (const float*)d_in[0];   // [8][2][256][256][100]
    const float* w0   = (const float*)d_in[1];   // [4][2][7][7][1]
    const float* w1   = (const float*)d_in[2];   // [8][4][7][7][1]
    const float* wd   = (const float*)d_in[3];   // [2][8][4][4][1]
    float* out = (float*)d_out;                  // [8][2][100]

    char* ws = (char*)d_ws;
    double*  pooled0 = (double*)(ws);                 // 52,428,800 B
    double*  x1      = (double*)(ws + 52428800);      // 16,384,000 B
    uint8_t* s0      = (uint8_t*)(ws + 68812800);     // 13,107,200 B
    float*   pooled1 = (float*)(ws + 81920000);       //  3,276,800 B
    uint8_t* s1      = (uint8_t*)(ws + 85196800);     //  2,048,000 B
    // total 87,244,800 B

    k1_pool0<<<1024, 256, 0, stream>>>(data, pooled0);
    k2_conv0_scan<<<512, 128, 0, stream>>>(pooled0, w0, s0);
    k3_pool1<<<3200, 256, 0, stream>>>(s0, pooled1);
    k4a_conv1<<<800, 256, 0, stream>>>(pooled1, w1, x1);
    k4b_scan1<<<64, 256, 0, stream>>>(x1, s1);
    k5_dense<<<800, 256, 0, stream>>>(s1, wd, out);
}

// Round 3
// 253.975 us; speedup vs baseline: 2.3567x; 2.3567x over previous
//
#include <hip/hip_runtime.h>
#include <hip/hip_bf16.h>
#include <stdint.h>

// SLAYER SNN pipeline, MI355X.
// Layouts: raw input NCHWT (t innermost). All intermediate activations NCTHW
// (spatial innermost) so conv tile loads and time-scan loads are coalesced.
// Precision: conv/cumsum/scan path in f64 (spike flips are the failure mode);
// loop nesting ci->kh->kw kept identical everywhere so results are bit-stable.
// Spikes stored as u8 (exact); spike pooling = int sum / 16 (exact in f32).

#define T_ 100

// ---------------- K1: avgpool4 on raw input, NCHWT -> NCTHW f64 --------------
__global__ __launch_bounds__(256) void k1_pool0(const float* __restrict__ in,
                                                double* __restrict__ out) {
    __shared__ double lds[64 * 101];
    int b = blockIdx.x;
    int h = b & 63, c = (b >> 6) & 1, n = b >> 7;
    const float* inb = in + ((size_t)((n * 2 + c) * 256 + 4 * h) * 256) * 100;
    for (int k = 0; k < 25; ++k) {
        int oi = threadIdx.x + (k << 8);       // 0..6399
        int w = oi / 100, t = oi % 100;
        double s = 0.0;
        #pragma unroll
        for (int a = 0; a < 4; ++a) {
            #pragma unroll
            for (int bb = 0; bb < 4; ++bb)
                s += (double)inb[((size_t)(a * 256 + 4 * w + bb)) * 100 + t];
        }
        lds[w * 101 + t] = s * 0.0625;
    }
    __syncthreads();
    double* outb = out + ((size_t)(n * 2 + c) * 100) * 4096 + h * 64;
    for (int k = 0; k < 25; ++k) {
        int oi = threadIdx.x + (k << 8);
        int t = oi >> 6, w = oi & 63;
        outb[(size_t)t * 4096 + w] = lds[w * 101 + t];
    }
}

// ------- K2a: conv7x7 (2->4ch) in f64, fully parallel over (n,t,h-slab) -----
// grid 3200 = 8n * 100t * 4hs, block 256 (hq,w). pooled0 -> x0 [8][4][100][4096] f64
__global__ __launch_bounds__(256) void k2a_conv0(const double* __restrict__ pooled0,
                                                 const float* __restrict__ wc0,
                                                 double* __restrict__ x0) {
    __shared__ double tile[2 * 22 * 70];   // 24640 B
    __shared__ double wlds[392];           // 4co x 2ci x 49
    int b = blockIdx.x;
    int hs = b & 3;
    int t = (b >> 2) % 100;
    int n = b / 400;
    int tid = threadIdx.x;

    // FIX(R2): block is 256 threads but 392 weights -> strided cooperative load.
    for (int i = tid; i < 392; i += 256) wlds[i] = (double)wc0[i];
    // load input tile: rows habs = hs*16-3 .. hs*16+18, cols -3..66 (zeros OOB)
    for (int k = 0; k < 13; ++k) {
        int e = tid + (k << 8);
        if (e < 3080) {
            int ci = e / 1540, rem = e % 1540;
            int row = rem / 70, ww = rem % 70;
            int habs = hs * 16 + row - 3;
            int wabs = ww - 3;
            double v = 0.0;
            if ((unsigned)habs < 64u && (unsigned)wabs < 64u)
                v = pooled0[((size_t)((n * 2 + ci) * 100 + t)) * 4096 + habs * 64 + wabs];
            tile[(ci * 22 + row) * 70 + ww] = v;
        }
    }
    __syncthreads();

    int w = tid & 63, hq = tid >> 6;       // hq 0..3 -> local h rows hq*4..hq*4+3
    int hl0 = hq * 4;
    double acc[4][4];                      // [co][j]
    #pragma unroll
    for (int co = 0; co < 4; ++co)
        #pragma unroll
        for (int j = 0; j < 4; ++j) acc[co][j] = 0.0;

    for (int ci = 0; ci < 2; ++ci) {
        for (int kh = 0; kh < 7; ++kh) {
            const double* r0 = &tile[(ci * 22 + hl0 + kh) * 70 + w];
            const double* wp = &wlds[ci * 49 + kh * 7];
            #pragma unroll
            for (int kw = 0; kw < 7; ++kw) {
                double v0 = r0[kw];
                double v1 = r0[70 + kw];
                double v2 = r0[140 + kw];
                double v3 = r0[210 + kw];
                #pragma unroll
                for (int co = 0; co < 4; ++co) {
                    double wv = wp[co * 98 + kw];
                    acc[co][0] += v0 * wv;
                    acc[co][1] += v1 * wv;
                    acc[co][2] += v2 * wv;
                    acc[co][3] += v3 * wv;
                }
            }
        }
    }
    #pragma unroll
    for (int co = 0; co < 4; ++co)
        #pragma unroll
        for (int j = 0; j < 4; ++j)
            x0[((size_t)((n * 4 + co) * 100 + t)) * 4096 + (hs * 16 + hl0 + j) * 64 + w] =
                acc[co][j];
}

// ------- K2b: cumsum + IAF scan for stage 1 (coalesced streaming) ------------
// grid 512 = 8n*4co*16, block 256. x0 f64 -> s0 u8 (same NCTHW layout)
__global__ __launch_bounds__(256) void k2b_scan0(const double* __restrict__ x0,
                                                 uint8_t* __restrict__ s0) {
    int bid = blockIdx.x;
    size_t base = (size_t)(bid >> 4) * (100 * 4096) + ((bid & 15) << 8) + threadIdx.x;
    double p = 0.0;
    int cnt = 0;
    #pragma unroll 4
    for (int t = 0; t < T_; ++t) {
        p += x0[base + (size_t)t * 4096];
        int sp = (p - (double)cnt) >= 1.0;
        cnt += sp;
        s0[base + (size_t)t * 4096] = (uint8_t)sp;
    }
}

// ------- K2 fused fallback (used only if ws_size is too small) ---------------
#define TC2 5
__global__ __launch_bounds__(128) void k2_conv0_scan(const double* __restrict__ pooled0,
                                                     const float* __restrict__ wc0,
                                                     uint8_t* __restrict__ s0) {
    __shared__ double tile[2 * 7 * TC2 * 70];
    int b = blockIdx.x;
    int h = b & 63, n = b >> 6;
    int tid = threadIdx.x;
    int w = tid & 63, cog = tid >> 6;
    int co0 = 2 * cog, co1 = co0 + 1;
    for (int i = tid; i < 2 * 7 * TC2 * 70; i += 128) tile[i] = 0.0;
    double p0 = 0.0, p1 = 0.0;
    int c0 = 0, c1 = 0;
    for (int ch = 0; ch < T_ / TC2; ++ch) {
        int t0 = ch * TC2;
        __syncthreads();
        for (int k = 0; k < 35; ++k) {
            int e = tid + (k << 7);
            int ww = e & 63, rowid = e >> 6;
            int ci = rowid / 35, rem = rowid % 35;
            int tt = rem / 7, r = rem % 7;
            int habs = h - 3 + r;
            if ((unsigned)habs < 64u)
                tile[((ci * 7 + r) * TC2 + tt) * 70 + ww + 3] =
                    pooled0[((size_t)((n * 2 + ci) * 100 + t0 + tt)) * 4096 + habs * 64 + ww];
        }
        __syncthreads();
        double acc0[TC2], acc1[TC2];
        #pragma unroll
        for (int tt = 0; tt < TC2; ++tt) { acc0[tt] = 0.0; acc1[tt] = 0.0; }
        for (int ci = 0; ci < 2; ++ci) {
            for (int kh = 0; kh < 7; ++kh) {
                const double* trow = &tile[((ci * 7 + kh) * TC2) * 70];
                const float* wr0 = &wc0[co0 * 98 + ci * 49 + kh * 7];
                const float* wr1 = &wc0[co1 * 98 + ci * 49 + kh * 7];
                #pragma unroll
                for (int kw = 0; kw < 7; ++kw) {
                    double wa = (double)wr0[kw];
                    double wb = (double)wr1[kw];
                    #pragma unroll
                    for (int tt = 0; tt < TC2; ++tt) {
                        double v = trow[tt * 70 + w + kw];
                        acc0[tt] += v * wa;
                        acc1[tt] += v * wb;
                    }
                }
            }
        }
        #pragma unroll
        for (int tt = 0; tt < TC2; ++tt) {
            size_t ob = ((size_t)((n * 4 + co0) * 100 + t0 + tt)) * 4096 + h * 64 + w;
            p0 += acc0[tt];
            int sp0 = (p0 - (double)c0) >= 1.0;
            c0 += sp0;
            s0[ob] = (uint8_t)sp0;
            size_t ob1 = ((size_t)((n * 4 + co1) * 100 + t0 + tt)) * 4096 + h * 64 + w;
            p1 += acc1[tt];
            int sp1 = (p1 - (double)c1) >= 1.0;
            c1 += sp1;
            s0[ob1] = (uint8_t)sp1;
        }
    }
}

// ---------------- K3: avgpool4 of spikes (exact) -----------------------------
__global__ __launch_bounds__(256) void k3_pool1(const uint8_t* __restrict__ s0,
                                                float* __restrict__ pooled1) {
    int oi = blockIdx.x * 256 + threadIdx.x;
    int w = oi & 15, h = (oi >> 4) & 15;
    int tc = oi >> 8;
    int t = tc % 100, nc = tc / 100;
    const uint8_t* base = s0 + ((size_t)nc * 100 + t) * 4096;
    int isum = 0;
    #pragma unroll
    for (int a = 0; a < 4; ++a) {
        #pragma unroll
        for (int bb = 0; bb < 4; ++bb)
            isum += base[(4 * h + a) * 64 + 4 * w + bb];
    }
    pooled1[oi] = (float)isum * 0.0625f;
}

// ---------------- K4a: conv7x7 (4->8ch) in f64 -------------------------------
__global__ __launch_bounds__(256) void k4a_conv1(const float* __restrict__ pooled1,
                                                 const float* __restrict__ wc1,
                                                 double* __restrict__ x1) {
    __shared__ float tile[4 * 22 * 24];
    int b = blockIdx.x;
    int n = b / 100, t = b % 100;
    int tid = threadIdx.x;
    for (int i = tid; i < 4 * 22 * 24; i += 256) tile[i] = 0.0f;
    __syncthreads();
    for (int k = 0; k < 4; ++k) {
        int e = tid + (k << 8);
        int w = e & 15, rowid = e >> 4;
        int ci = rowid >> 4, hr3 = rowid & 15;
        tile[(ci * 22 + hr3 + 3) * 24 + 3 + w] =
            pooled1[((size_t)((n * 4 + ci) * 100 + t)) * 256 + hr3 * 16 + w];
    }
    __syncthreads();
    int h = tid >> 4, w = tid & 15;
    double acc[8];
    #pragma unroll
    for (int co = 0; co < 8; ++co) acc[co] = 0.0;
    for (int ci = 0; ci < 4; ++ci) {
        for (int kh = 0; kh < 7; ++kh) {
            const float* trow = &tile[(ci * 22 + h + kh) * 24];
            const float* wr = &wc1[ci * 49 + kh * 7];
            #pragma unroll
            for (int kw = 0; kw < 7; ++kw) {
                double v = (double)trow[w + kw];
                #pragma unroll
                for (int co = 0; co < 8; ++co)
                    acc[co] += v * (double)wr[co * 196 + kw];
            }
        }
    }
    #pragma unroll
    for (int co = 0; co < 8; ++co)
        x1[((size_t)((n * 8 + co) * 100 + t)) * 256 + tid] = acc[co];
}

// ---------------- K4b: cumsum + IAF scan for stage 2 -------------------------
__global__ __launch_bounds__(256) void k4b_scan1(const double* __restrict__ x1,
                                                 uint8_t* __restrict__ s1) {
    size_t base = (size_t)blockIdx.x * 100 * 256 + threadIdx.x;
    double p = 0.0;
    int cnt = 0;
    #pragma unroll 4
    for (int t = 0; t < T_; ++t) {
        p += x1[base + (size_t)t * 256];
        int sp = (p - (double)cnt) >= 1.0;
        cnt += sp;
        s1[base + (size_t)t * 256] = (uint8_t)sp;
    }
}

// ---------------- K5: avgpool4 + dense, fused block reduction ----------------
__global__ __launch_bounds__(256) void k5_dense(const uint8_t* __restrict__ s1,
                                                const float* __restrict__ wd,
                                                float* __restrict__ out) {
    __shared__ float red[2][4];
    int b = blockIdx.x;
    int n = b / 100, t = b % 100;
    int tid = threadIdx.x;
    int c = tid >> 5, H = (tid >> 1) & 15, Wg = tid & 1;
    const uint8_t* sb = s1 + ((size_t)((n * 8 + c) * 100 + t)) * 256 + H * 16 + Wg * 8;
    float sumA = 0.f, sumB = 0.f;
    #pragma unroll
    for (int j = 0; j < 4; ++j) sumA += (float)sb[j];
    #pragma unroll
    for (int j = 4; j < 8; ++j) sumB += (float)sb[j];
    int wb = c * 16 + (H >> 2) * 4 + Wg * 2;
    float o0 = sumA * wd[wb] + sumB * wd[wb + 1];
    float o1 = sumA * wd[128 + wb] + sumB * wd[128 + wb + 1];
    #pragma unroll
    for (int off = 32; off > 0; off >>= 1) {
        o0 += __shfl_down(o0, off, 64);
        o1 += __shfl_down(o1, off, 64);
    }
    int lane = tid & 63, wid = tid >> 6;
    if (lane == 0) { red[0][wid] = o0; red[1][wid] = o1; }
    __syncthreads();
    if (tid == 0) {
        float a = (red[0][0] + red[0][1]) + (red[0][2] + red[0][3]);
        float bsum = (red[1][0] + red[1][1]) + (red[1][2] + red[1][3]);
        out[(size_t)(n * 2) * 100 + t] = a * 0.0625f;
        out[(size_t)(n * 2 + 1) * 100 + t] = bsum * 0.0625f;
    }
}

extern "C" void kernel_launch(void* const* d_in, const int* in_sizes, int n_in,
                              void* d_out, int out_size, void* d_ws, size_t ws_size,
                              hipStream_t stream) {
    const float* data = (const float*)d_in[0];
    const float* w0   = (const float*)d_in[1];
    const float* w1   = (const float*)d_in[2];
    const float* wd   = (const float*)d_in[3];
    float* out = (float*)d_out;
    char* ws = (char*)d_ws;

    const size_t NEED_SPLIT = 157286400;  // pooled0(52.4M) + x0(104.9M)

    if (ws_size >= NEED_SPLIT) {
        // split path: x0 materialized; later buffers alias pooled0's region
        double*  pooled0 = (double*)(ws);                 // [0, 52428800)
        double*  x0      = (double*)(ws + 52428800);      // [52428800, 157286400)
        uint8_t* s0      = (uint8_t*)(ws);                // alias pooled0 (dead)
        float*   pooled1 = (float*)(ws + 13107200);
        double*  x1      = (double*)(ws + 16384000);
        uint8_t* s1      = (uint8_t*)(ws + 32768000);

        k1_pool0<<<1024, 256, 0, stream>>>(data, pooled0);
        k2a_conv0<<<3200, 256, 0, stream>>>(pooled0, w0, x0);
        k2b_scan0<<<512, 256, 0, stream>>>(x0, s0);
        k3_pool1<<<3200, 256, 0, stream>>>(s0, pooled1);
        k4a_conv1<<<800, 256, 0, stream>>>(pooled1, w1, x1);
        k4b_scan1<<<64, 256, 0, stream>>>(x1, s1);
        k5_dense<<<800, 256, 0, stream>>>(s1, wd, out);
    } else {
        // fallback: fused conv0+scan (slower but fits 87.2 MB)
        double*  pooled0 = (double*)(ws);
        double*  x1      = (double*)(ws + 52428800);
        uint8_t* s0      = (uint8_t*)(ws + 68812800);
        float*   pooled1 = (float*)(ws + 81920000);
        uint8_t* s1      = (uint8_t*)(ws + 85196800);

        k1_pool0<<<1024, 256, 0, stream>>>(data, pooled0);
        k2_conv0_scan<<<512, 128, 0, stream>>>(pooled0, w0, s0);
        k3_pool1<<<3200, 256, 0, stream>>>(s0, pooled1);
        k4a_conv1<<<800, 256, 0, stream>>>(pooled1, w1, x1);
        k4b_scan1<<<64, 256, 0, stream>>>(x1, s1);
        k5_dense<<<800, 256, 0, stream>>>(s1, wd, out);
    }
}

// Round 4
// 244.323 us; speedup vs baseline: 2.4498x; 1.0395x over previous
//
#include <hip/hip_runtime.h>
#include <hip/hip_bf16.h>
#include <stdint.h>

// SLAYER SNN pipeline, MI355X.
// Layouts: raw input NCHWT (t innermost). All intermediate activations NCTHW
// (spatial innermost) so conv tile loads and time-scan loads are coalesced.
// Precision: conv/cumsum/scan path in f64. CRITICAL: absmax is 0.0195 vs
// threshold 0.0208 -> per-output FP accumulation order must stay EXACTLY
// fixed (ci->kh->kw, a->bb, t ascending). Data-movement changes only.
// Spikes stored as u8 (exact); spike pooling = int sum / 16 (exact in f32).

#define T_ 100

// ---------------- K1: avgpool4 on raw input, NCHWT -> NCTHW f64 --------------
// grid 1024 (n,c,h'), block 256. float4-vectorized reads (4 t's per load).
__global__ __launch_bounds__(256) void k1_pool0(const float* __restrict__ in,
                                                double* __restrict__ out) {
    __shared__ double lds[64 * 101];
    int b = blockIdx.x;
    int h = b & 63, c = (b >> 6) & 1, n = b >> 7;
    const float* inb = in + ((size_t)((n * 2 + c) * 256 + 4 * h) * 256) * 100;
    // phase A: 1600 items = 64 w x 25 tq (4 t's each), float4 loads
    for (int k = 0; k < 7; ++k) {
        int e = threadIdx.x + (k << 8);
        if (e < 1600) {
            int w = e / 25, tq = e % 25;
            double s0 = 0.0, s1 = 0.0, s2 = 0.0, s3 = 0.0;
            #pragma unroll
            for (int a = 0; a < 4; ++a) {
                #pragma unroll
                for (int bb = 0; bb < 4; ++bb) {
                    const float4 v = *reinterpret_cast<const float4*>(
                        &inb[((size_t)(a * 256 + 4 * w + bb)) * 100 + 4 * tq]);
                    s0 += (double)v.x;   // same a->bb order as scalar version
                    s1 += (double)v.y;
                    s2 += (double)v.z;
                    s3 += (double)v.w;
                }
            }
            double* lp = &lds[w * 101 + 4 * tq];
            lp[0] = s0 * 0.0625;
            lp[1] = s1 * 0.0625;
            lp[2] = s2 * 0.0625;
            lp[3] = s3 * 0.0625;
        }
    }
    __syncthreads();
    // phase B: write NCTHW (lanes consecutive in w -> coalesced 512B stores)
    double* outb = out + ((size_t)(n * 2 + c) * 100) * 4096 + h * 64;
    for (int k = 0; k < 25; ++k) {
        int oi = threadIdx.x + (k << 8);
        int t = oi >> 6, w = oi & 63;
        outb[(size_t)t * 4096 + w] = lds[w * 101 + t];
    }
}

// ------- K2a: conv7x7 (2->4ch) in f64, fully parallel over (n,t,h-slab) -----
// grid 3200 = 8n * 100t * 4hs, block 256 (hq,w). pooled0 -> x0 [8][4][100][4096] f64
__global__ __launch_bounds__(256) void k2a_conv0(const double* __restrict__ pooled0,
                                                 const float* __restrict__ wc0,
                                                 double* __restrict__ x0) {
    __shared__ double tile[2 * 22 * 70];   // 24640 B
    __shared__ double wlds[392];           // 4co x 2ci x 49
    int b = blockIdx.x;
    int hs = b & 3;
    int t = (b >> 2) % 100;
    int n = b / 400;
    int tid = threadIdx.x;

    for (int i = tid; i < 392; i += 256) wlds[i] = (double)wc0[i];
    // load input tile: rows habs = hs*16-3 .. hs*16+18, cols -3..66 (zeros OOB)
    for (int k = 0; k < 13; ++k) {
        int e = tid + (k << 8);
        if (e < 3080) {
            int ci = e / 1540, rem = e % 1540;
            int row = rem / 70, ww = rem % 70;
            int habs = hs * 16 + row - 3;
            int wabs = ww - 3;
            double v = 0.0;
            if ((unsigned)habs < 64u && (unsigned)wabs < 64u)
                v = pooled0[((size_t)((n * 2 + ci) * 100 + t)) * 4096 + habs * 64 + wabs];
            tile[(ci * 22 + row) * 70 + ww] = v;
        }
    }
    __syncthreads();

    int w = tid & 63, hq = tid >> 6;       // hq 0..3 -> local h rows hq*4..hq*4+3
    int hl0 = hq * 4;
    double acc[4][4];                      // [co][j]
    #pragma unroll
    for (int co = 0; co < 4; ++co)
        #pragma unroll
        for (int j = 0; j < 4; ++j) acc[co][j] = 0.0;

    for (int ci = 0; ci < 2; ++ci) {
        for (int kh = 0; kh < 7; ++kh) {
            const double* r0 = &tile[(ci * 22 + hl0 + kh) * 70 + w];
            const double* wp = &wlds[ci * 49 + kh * 7];
            #pragma unroll
            for (int kw = 0; kw < 7; ++kw) {
                double v0 = r0[kw];
                double v1 = r0[70 + kw];
                double v2 = r0[140 + kw];
                double v3 = r0[210 + kw];
                #pragma unroll
                for (int co = 0; co < 4; ++co) {
                    double wv = wp[co * 98 + kw];
                    acc[co][0] += v0 * wv;
                    acc[co][1] += v1 * wv;
                    acc[co][2] += v2 * wv;
                    acc[co][3] += v3 * wv;
                }
            }
        }
    }
    #pragma unroll
    for (int co = 0; co < 4; ++co)
        #pragma unroll
        for (int j = 0; j < 4; ++j)
            x0[((size_t)((n * 4 + co) * 100 + t)) * 4096 + (hs * 16 + hl0 + j) * 64 + w] =
                acc[co][j];
}

// ------- K2b: cumsum + IAF scan for stage 1 (chunked register prefetch) ------
// grid 512 = 8n*4co*16, block 256. x0 f64 -> s0 u8 (same NCTHW layout)
__global__ __launch_bounds__(256) void k2b_scan0(const double* __restrict__ x0,
                                                 uint8_t* __restrict__ s0) {
    int bid = blockIdx.x;
    size_t base = (size_t)(bid >> 4) * (100 * 4096) + ((bid & 15) << 8) + threadIdx.x;
    double p = 0.0;
    int cnt = 0;
    for (int tc = 0; tc < 10; ++tc) {
        double v[10];
        #pragma unroll
        for (int j = 0; j < 10; ++j)
            v[j] = x0[base + (size_t)(tc * 10 + j) * 4096];   // 10 loads in flight
        #pragma unroll
        for (int j = 0; j < 10; ++j) {
            p += v[j];                                         // same t order
            int sp = (p - (double)cnt) >= 1.0;
            cnt += sp;
            s0[base + (size_t)(tc * 10 + j) * 4096] = (uint8_t)sp;
        }
    }
}

// ------- K2 fused fallback (used only if ws_size is too small) ---------------
#define TC2 5
__global__ __launch_bounds__(128) void k2_conv0_scan(const double* __restrict__ pooled0,
                                                     const float* __restrict__ wc0,
                                                     uint8_t* __restrict__ s0) {
    __shared__ double tile[2 * 7 * TC2 * 70];
    int b = blockIdx.x;
    int h = b & 63, n = b >> 6;
    int tid = threadIdx.x;
    int w = tid & 63, cog = tid >> 6;
    int co0 = 2 * cog, co1 = co0 + 1;
    for (int i = tid; i < 2 * 7 * TC2 * 70; i += 128) tile[i] = 0.0;
    double p0 = 0.0, p1 = 0.0;
    int c0 = 0, c1 = 0;
    for (int ch = 0; ch < T_ / TC2; ++ch) {
        int t0 = ch * TC2;
        __syncthreads();
        for (int k = 0; k < 35; ++k) {
            int e = tid + (k << 7);
            int ww = e & 63, rowid = e >> 6;
            int ci = rowid / 35, rem = rowid % 35;
            int tt = rem / 7, r = rem % 7;
            int habs = h - 3 + r;
            if ((unsigned)habs < 64u)
                tile[((ci * 7 + r) * TC2 + tt) * 70 + ww + 3] =
                    pooled0[((size_t)((n * 2 + ci) * 100 + t0 + tt)) * 4096 + habs * 64 + ww];
        }
        __syncthreads();
        double acc0[TC2], acc1[TC2];
        #pragma unroll
        for (int tt = 0; tt < TC2; ++tt) { acc0[tt] = 0.0; acc1[tt] = 0.0; }
        for (int ci = 0; ci < 2; ++ci) {
            for (int kh = 0; kh < 7; ++kh) {
                const double* trow = &tile[((ci * 7 + kh) * TC2) * 70];
                const float* wr0 = &wc0[co0 * 98 + ci * 49 + kh * 7];
                const float* wr1 = &wc0[co1 * 98 + ci * 49 + kh * 7];
                #pragma unroll
                for (int kw = 0; kw < 7; ++kw) {
                    double wa = (double)wr0[kw];
                    double wb = (double)wr1[kw];
                    #pragma unroll
                    for (int tt = 0; tt < TC2; ++tt) {
                        double v = trow[tt * 70 + w + kw];
                        acc0[tt] += v * wa;
                        acc1[tt] += v * wb;
                    }
                }
            }
        }
        #pragma unroll
        for (int tt = 0; tt < TC2; ++tt) {
            size_t ob = ((size_t)((n * 4 + co0) * 100 + t0 + tt)) * 4096 + h * 64 + w;
            p0 += acc0[tt];
            int sp0 = (p0 - (double)c0) >= 1.0;
            c0 += sp0;
            s0[ob] = (uint8_t)sp0;
            size_t ob1 = ((size_t)((n * 4 + co1) * 100 + t0 + tt)) * 4096 + h * 64 + w;
            p1 += acc1[tt];
            int sp1 = (p1 - (double)c1) >= 1.0;
            c1 += sp1;
            s0[ob1] = (uint8_t)sp1;
        }
    }
}

// ---------------- K3: avgpool4 of spikes (exact, u32 packed reads) -----------
__global__ __launch_bounds__(256) void k3_pool1(const uint8_t* __restrict__ s0,
                                                float* __restrict__ pooled1) {
    int oi = blockIdx.x * 256 + threadIdx.x;
    int w = oi & 15, h = (oi >> 4) & 15;
    int tc = oi >> 8;
    int t = tc % 100, nc = tc / 100;
    const uint8_t* base = s0 + ((size_t)nc * 100 + t) * 4096;
    int isum = 0;
    #pragma unroll
    for (int a = 0; a < 4; ++a) {
        uint32_t v = *reinterpret_cast<const uint32_t*>(&base[(4 * h + a) * 64 + 4 * w]);
        isum += (int)(v & 0xffu) + (int)((v >> 8) & 0xffu) +
                (int)((v >> 16) & 0xffu) + (int)(v >> 24);
    }
    pooled1[oi] = (float)isum * 0.0625f;
}

// ---------------- K4a: conv7x7 (4->8ch) in f64 -------------------------------
__global__ __launch_bounds__(256) void k4a_conv1(const float* __restrict__ pooled1,
                                                 const float* __restrict__ wc1,
                                                 double* __restrict__ x1) {
    __shared__ float tile[4 * 22 * 24];
    int b = blockIdx.x;
    int n = b / 100, t = b % 100;
    int tid = threadIdx.x;
    for (int i = tid; i < 4 * 22 * 24; i += 256) tile[i] = 0.0f;
    __syncthreads();
    for (int k = 0; k < 4; ++k) {
        int e = tid + (k << 8);
        int w = e & 15, rowid = e >> 4;
        int ci = rowid >> 4, hr3 = rowid & 15;
        tile[(ci * 22 + hr3 + 3) * 24 + 3 + w] =
            pooled1[((size_t)((n * 4 + ci) * 100 + t)) * 256 + hr3 * 16 + w];
    }
    __syncthreads();
    int h = tid >> 4, w = tid & 15;
    double acc[8];
    #pragma unroll
    for (int co = 0; co < 8; ++co) acc[co] = 0.0;
    for (int ci = 0; ci < 4; ++ci) {
        for (int kh = 0; kh < 7; ++kh) {
            const float* trow = &tile[(ci * 22 + h + kh) * 24];
            const float* wr = &wc1[ci * 49 + kh * 7];
            #pragma unroll
            for (int kw = 0; kw < 7; ++kw) {
                double v = (double)trow[w + kw];
                #pragma unroll
                for (int co = 0; co < 8; ++co)
                    acc[co] += v * (double)wr[co * 196 + kw];
            }
        }
    }
    #pragma unroll
    for (int co = 0; co < 8; ++co)
        x1[((size_t)((n * 8 + co) * 100 + t)) * 256 + tid] = acc[co];
}

// ---------------- K4b: cumsum + IAF scan for stage 2 (chunked prefetch) ------
__global__ __launch_bounds__(256) void k4b_scan1(const double* __restrict__ x1,
                                                 uint8_t* __restrict__ s1) {
    size_t base = (size_t)blockIdx.x * 100 * 256 + threadIdx.x;
    double p = 0.0;
    int cnt = 0;
    for (int tc = 0; tc < 10; ++tc) {
        double v[10];
        #pragma unroll
        for (int j = 0; j < 10; ++j)
            v[j] = x1[base + (size_t)(tc * 10 + j) * 256];
        #pragma unroll
        for (int j = 0; j < 10; ++j) {
            p += v[j];
            int sp = (p - (double)cnt) >= 1.0;
            cnt += sp;
            s1[base + (size_t)(tc * 10 + j) * 256] = (uint8_t)sp;
        }
    }
}

// ---------------- K5: avgpool4 + dense, fused block reduction ----------------
__global__ __launch_bounds__(256) void k5_dense(const uint8_t* __restrict__ s1,
                                                const float* __restrict__ wd,
                                                float* __restrict__ out) {
    __shared__ float red[2][4];
    int b = blockIdx.x;
    int n = b / 100, t = b % 100;
    int tid = threadIdx.x;
    int c = tid >> 5, H = (tid >> 1) & 15, Wg = tid & 1;
    const uint8_t* sb = s1 + ((size_t)((n * 8 + c) * 100 + t)) * 256 + H * 16 + Wg * 8;
    float sumA = 0.f, sumB = 0.f;
    #pragma unroll
    for (int j = 0; j < 4; ++j) sumA += (float)sb[j];
    #pragma unroll
    for (int j = 4; j < 8; ++j) sumB += (float)sb[j];
    int wb = c * 16 + (H >> 2) * 4 + Wg * 2;
    float o0 = sumA * wd[wb] + sumB * wd[wb + 1];
    float o1 = sumA * wd[128 + wb] + sumB * wd[128 + wb + 1];
    #pragma unroll
    for (int off = 32; off > 0; off >>= 1) {
        o0 += __shfl_down(o0, off, 64);
        o1 += __shfl_down(o1, off, 64);
    }
    int lane = tid & 63, wid = tid >> 6;
    if (lane == 0) { red[0][wid] = o0; red[1][wid] = o1; }
    __syncthreads();
    if (tid == 0) {
        float a = (red[0][0] + red[0][1]) + (red[0][2] + red[0][3]);
        float bsum = (red[1][0] + red[1][1]) + (red[1][2] + red[1][3]);
        out[(size_t)(n * 2) * 100 + t] = a * 0.0625f;
        out[(size_t)(n * 2 + 1) * 100 + t] = bsum * 0.0625f;
    }
}

extern "C" void kernel_launch(void* const* d_in, const int* in_sizes, int n_in,
                              void* d_out, int out_size, void* d_ws, size_t ws_size,
                              hipStream_t stream) {
    const float* data = (const float*)d_in[0];
    const float* w0   = (const float*)d_in[1];
    const float* w1   = (const float*)d_in[2];
    const float* wd   = (const float*)d_in[3];
    float* out = (float*)d_out;
    char* ws = (char*)d_ws;

    const size_t NEED_SPLIT = 157286400;  // pooled0(52.4M) + x0(104.9M)

    if (ws_size >= NEED_SPLIT) {
        // split path: x0 materialized; later buffers alias pooled0's region
        double*  pooled0 = (double*)(ws);                 // [0, 52428800)
        double*  x0      = (double*)(ws + 52428800);      // [52428800, 157286400)
        uint8_t* s0      = (uint8_t*)(ws);                // alias pooled0 (dead)
        float*   pooled1 = (float*)(ws + 13107200);
        double*  x1      = (double*)(ws + 16384000);
        uint8_t* s1      = (uint8_t*)(ws + 32768000);

        k1_pool0<<<1024, 256, 0, stream>>>(data, pooled0);
        k2a_conv0<<<3200, 256, 0, stream>>>(pooled0, w0, x0);
        k2b_scan0<<<512, 256, 0, stream>>>(x0, s0);
        k3_pool1<<<3200, 256, 0, stream>>>(s0, pooled1);
        k4a_conv1<<<800, 256, 0, stream>>>(pooled1, w1, x1);
        k4b_scan1<<<64, 256, 0, stream>>>(x1, s1);
        k5_dense<<<800, 256, 0, stream>>>(s1, wd, out);
    } else {
        // fallback: fused conv0+scan (slower but fits 87.2 MB)
        double*  pooled0 = (double*)(ws);
        double*  x1      = (double*)(ws + 52428800);
        uint8_t* s0      = (uint8_t*)(ws + 68812800);
        float*   pooled1 = (float*)(ws + 81920000);
        uint8_t* s1      = (uint8_t*)(ws + 85196800);

        k1_pool0<<<1024, 256, 0, stream>>>(data, pooled0);
        k2_conv0_scan<<<512, 128, 0, stream>>>(pooled0, w0, s0);
        k3_pool1<<<3200, 256, 0, stream>>>(s0, pooled1);
        k4a_conv1<<<800, 256, 0, stream>>>(pooled1, w1, x1);
        k4b_scan1<<<64, 256, 0, stream>>>(x1, s1);
        k5_dense<<<800, 256, 0, stream>>>(s1, wd, out);
    }
}